// Round 1
// baseline (8412.482 us; speedup 1.0000x reference)
//
#include <hip/hip_runtime.h>

// NeuralCDE: B=1024,S=64,F=16,H=128. Persistent kernel, one wg = NB batches,
// full 63-step / 4-stage RK loop in-kernel. Round 1: pure fp32 (correctness
// baseline). W2 streamed from L2 (1MB, L2-resident per XCD).

#define NT 512          // threads per workgroup (8 waves)
#define NB 8            // batches per workgroup -> 128 workgroups

__global__ __launch_bounds__(NT, 2) void cde_fp32_kernel(
    const float* __restrict__ x,
    const float* __restrict__ W1,
    const float* __restrict__ b1,
    const float* __restrict__ W2,
    const float* __restrict__ b2,
    const float* __restrict__ Wi,
    const float* __restrict__ bi,
    float* __restrict__ out)
{
    const int H = 128, F = 16, S = 64;
    // LDS budget: 64K + 32K + 16K + 3*4K + 2K = 126 KiB (one wg/CU)
    __shared__ float sW1T[128 * 128];     // W1T[j*128+k] = W1[k][j]
    __shared__ float sx[NB * 64 * 16];    // x slice [b][s][f]
    __shared__ float skS[4 * NB * 128];   // k1..k4 [s][b][j]
    __shared__ float shT[128 * NB];       // state h, [j][b] (batch fastest)
    __shared__ float shsT[128 * NB];      // stage input h_s, [j][b]
    __shared__ float szT[128 * NB];       // z = tanh(...), [k][b]
    __shared__ float sdX[4 * NB * 16];    // dX at 4 RK nodes [s][b][f]

    const int t = threadIdx.x;
    const int b_base = blockIdx.x * NB;
    const float dt  = 1.0f / 63.0f;
    const float rdt = 63.0f;

    // ---- init: W1 transposed into LDS (transposed global read -> conflict-free LDS write)
    for (int idx = t; idx < H * H; idx += NT) {
        const int j = idx >> 7, k = idx & 127;
        sW1T[j * 128 + k] = W1[k * 128 + j];
    }
    // ---- x slice (coalesced)
    for (int idx = t; idx < NB * S * F; idx += NT)
        sx[idx] = x[(size_t)b_base * (S * F) + idx];
    __syncthreads();

    // ---- h0 = x[:,0] @ Wi^T + bi
    for (int idx = t; idx < H * NB; idx += NT) {
        const int j = idx & 127, b = idx >> 7;
        float acc = bi[j];
#pragma unroll
        for (int f = 0; f < 16; ++f)
            acc = fmaf(Wi[j * 16 + f], sx[b * (S * F) + f], acc);
        shT[j * NB + b]  = acc;
        shsT[j * NB + b] = acc;
    }

    // ---- time loop (63 intervals, strictly sequential)
    for (int i = 0; i < S - 1; ++i) {
        // Hermite cubic (backward differences) -> dX at the 4 RK nodes.
        // t encodes (s=t>>7, b=(t>>4)&7, f=t&15); sdX index == t exactly.
        {
            const int f = t & 15, b = (t >> 4) & 7, s = t >> 7;
            const float* xb = &sx[b * (S * F)];
            const float x0  = xb[i * 16 + f];
            const float x1  = xb[(i + 1) * 16 + f];
            const float seg = (x1 - x0) * rdt;
            const float m0  = (i == 0) ? seg : (x0 - xb[(i - 1) * 16 + f]) * rdt;
            // m1 = seg;  c = (3seg-(2m0+m1))/dt = 2(seg-m0)/dt ; d = (m0-seg)/dt^2
            const float c  = (2.0f * seg - 2.0f * m0) * rdt;
            const float d  = (m0 - seg) * rdt * rdt;
            const float ft = (float)s * (dt * (1.0f / 3.0f)); // 0, dt/3, 2dt/3, dt
            sdX[t] = fmaf(fmaf(3.0f * d, ft, 2.0f * c), ft, m0);
        }

        for (int s = 0; s < 4; ++s) {
            __syncthreads();  // hsT (+ sdX for s==0) ready

            // GEMM1: z[b][k] = tanh(b1[k] + sum_j W1[k][j] * hs[b][j])
            {
                const int k = t & 127, b0 = t >> 7;  // b0 in 0..3, pairs with b0+4
                float a0 = b1[k];
                float a1 = a0;
#pragma unroll 8
                for (int j = 0; j < 128; ++j) {
                    const float w = sW1T[j * 128 + k];       // stride-1 across lanes
                    a0 = fmaf(w, shsT[j * NB + b0], a0);     // wave-uniform broadcast
                    a1 = fmaf(w, shsT[j * NB + b0 + 4], a1);
                }
                szT[k * NB + b0]     = tanhf(a0);
                szT[k * NB + b0 + 4] = tanhf(a1);
            }
            __syncthreads();

            // GEMM2 + F-contraction: thread owns 4 contiguous W2 rows, all of ONE h
            {
                const int p  = t & 3;    // f-quarter
                const int h  = t >> 2;
                const int r0 = t * 4;    // rows r0..r0+3; f_j = p*4+j
                float acc[4][NB];
#pragma unroll
                for (int j = 0; j < 4; ++j)
#pragma unroll
                    for (int b = 0; b < NB; ++b) acc[j][b] = 0.0f;

                const float* w2p = &W2[(size_t)r0 * 128];
#pragma unroll 4
                for (int k0 = 0; k0 < 128; k0 += 4) {
                    float zc[4][NB];
#pragma unroll
                    for (int kk = 0; kk < 4; ++kk) {  // uniform-address b128 broadcasts
                        *(float4*)&zc[kk][0] = *(const float4*)&szT[(k0 + kk) * NB];
                        *(float4*)&zc[kk][4] = *(const float4*)&szT[(k0 + kk) * NB + 4];
                    }
#pragma unroll
                    for (int j = 0; j < 4; ++j) {
                        const float4 w = *(const float4*)&w2p[j * 128 + k0];
#pragma unroll
                        for (int b = 0; b < NB; ++b) {
                            acc[j][b] = fmaf(w.x, zc[0][b], acc[j][b]);
                            acc[j][b] = fmaf(w.y, zc[1][b], acc[j][b]);
                            acc[j][b] = fmaf(w.z, zc[2][b], acc[j][b]);
                            acc[j][b] = fmaf(w.w, zc[3][b], acc[j][b]);
                        }
                    }
                }
                const float4 bb = *(const float4*)&b2[r0];
                const float bbv[4] = {bb.x, bb.y, bb.z, bb.w};
                float kacc[NB];
#pragma unroll
                for (int b = 0; b < NB; ++b) kacc[b] = 0.0f;
#pragma unroll
                for (int j = 0; j < 4; ++j) {
                    const int fj = p * 4 + j;
#pragma unroll
                    for (int b = 0; b < NB; ++b)
                        kacc[b] = fmaf(sdX[s * (NB * 16) + b * 16 + fj],
                                       acc[j][b] + bbv[j], kacc[b]);
                }
#pragma unroll
                for (int b = 0; b < NB; ++b) {  // reduce the 4 f-quarters
                    kacc[b] += __shfl_xor(kacc[b], 1);
                    kacc[b] += __shfl_xor(kacc[b], 2);
                }
                if (p == 0) {
#pragma unroll
                    for (int b = 0; b < NB; ++b)
                        skS[s * (NB * 128) + b * 128 + h] = kacc[b];
                }
            }
            __syncthreads();

            // stage update (RK 3/8 rule)
            if (s == 3) {
                for (int idx = t; idx < 128 * NB; idx += NT) {
                    const int j = idx & 127, b = idx >> 7;
                    const float k1 = skS[0 * (NB * 128) + b * 128 + j];
                    const float k2 = skS[1 * (NB * 128) + b * 128 + j];
                    const float k3 = skS[2 * (NB * 128) + b * 128 + j];
                    const float k4 = skS[3 * (NB * 128) + b * 128 + j];
                    const float nh = shT[j * NB + b]
                                   + dt * 0.125f * (k1 + 3.0f * (k2 + k3) + k4);
                    shT[j * NB + b]  = nh;
                    shsT[j * NB + b] = nh;
                }
            } else {
                for (int idx = t; idx < 128 * NB; idx += NT) {
                    const int j = idx & 127, b = idx >> 7;
                    const float hv = shT[j * NB + b];
                    const float k1 = skS[0 * (NB * 128) + b * 128 + j];
                    float nh;
                    if (s == 0) {
                        nh = fmaf(dt * (1.0f / 3.0f), k1, hv);
                    } else if (s == 1) {
                        const float k2 = skS[1 * (NB * 128) + b * 128 + j];
                        nh = hv + dt * k2 - (dt * (1.0f / 3.0f)) * k1;
                    } else {
                        const float k2 = skS[1 * (NB * 128) + b * 128 + j];
                        const float k3 = skS[2 * (NB * 128) + b * 128 + j];
                        nh = fmaf(dt, (k1 - k2 + k3), hv);
                    }
                    shsT[j * NB + b] = nh;
                }
            }
        }
    }
    __syncthreads();

    // ---- write hT (coalesced across j)
    for (int idx = t; idx < 128 * NB; idx += NT) {
        const int j = idx & 127, b = idx >> 7;
        out[(size_t)(b_base + b) * 128 + j] = shT[j * NB + b];
    }
}

extern "C" void kernel_launch(void* const* d_in, const int* in_sizes, int n_in,
                              void* d_out, int out_size, void* d_ws, size_t ws_size,
                              hipStream_t stream)
{
    (void)in_sizes; (void)n_in; (void)d_ws; (void)ws_size; (void)out_size;
    const float* x  = (const float*)d_in[0];
    const float* W1 = (const float*)d_in[1];
    const float* b1 = (const float*)d_in[2];
    const float* W2 = (const float*)d_in[3];
    const float* b2 = (const float*)d_in[4];
    const float* Wi = (const float*)d_in[5];
    const float* bi = (const float*)d_in[6];
    float* o = (float*)d_out;
    hipLaunchKernelGGL(cde_fp32_kernel, dim3(1024 / NB), dim3(NT), 0, stream,
                       x, W1, b1, W2, b2, Wi, bi, o);
}

// Round 2
// 3276.143 us; speedup vs baseline: 2.5678x; 2.5678x over previous
//
#include <hip/hip_runtime.h>

// NeuralCDE B=1024,S=64,F=16,H=128. Persistent fp32 kernel.
// Round 2: W2 repacked in d_ws into per-lane streaming order (coalesced 1KB
// wave reads from L2), NT=1024 (16 waves/CU), NB=4 (256 wgs = all CUs),
// W1 packed in LDS lane-consecutive, z in [b][k] layout (uniform b128 reads).

#define NT 1024

// Pack W2[2048][128] -> PW2 slot (kc*2+j)*1024 + t  = float4{W2[row=t*2+j, k=kc*4..+3]}
__global__ void pack_w2_kernel(const float* __restrict__ W2, float4* __restrict__ PW2) {
    const int q = blockIdx.x * blockDim.x + threadIdx.x;   // 0..65535
    const int t = q & 1023, j = (q >> 10) & 1, kc = q >> 11;
    PW2[q] = *(const float4*)&W2[((t * 2 + j) << 7) + (kc << 2)];
}

template<bool PACKED>
__global__ __launch_bounds__(NT) void cde_kernel(
    const float* __restrict__ x,  const float* __restrict__ W1,
    const float* __restrict__ b1, const float* __restrict__ W2,
    const float* __restrict__ b2, const float* __restrict__ Wi,
    const float* __restrict__ bi, const float4* __restrict__ PW2,
    float* __restrict__ out)
{
    // LDS: 64K + 16K + 2K + 2K + 2K + 8K + 1K = 95.25 KiB (1 wg/CU; 256 wgs total)
    __shared__ float pW1[32 * 128 * 4];   // pW1[j4*512 + k*4 + jj] = W1[k][j4*4+jj]
    __shared__ float sx[4 * 64 * 16];     // x slice [b][s][f]
    __shared__ float zB[4 * 128];         // z, [b][k] (GEMM1 writes lane-consec, GEMM2 uniform b128)
    __shared__ float hB[4 * 128];         // state h [b][j]
    __shared__ float hsB[4 * 128];        // stage input [b][j]
    __shared__ float skS[4 * 4 * 128];    // k1..k4 [s][b][j]
    __shared__ float sdX[4 * 4 * 16];     // dX at 4 RK nodes [s][b][f]

    const int t = threadIdx.x;
    const int b_base = blockIdx.x * 4;
    const float dt = 1.0f / 63.0f, rdt = 63.0f;

    // ---- stage x (coalesced) + pack W1 into LDS
    for (int idx = t; idx < 4096; idx += NT) sx[idx] = x[(size_t)b_base * 1024 + idx];
    for (int idx = t; idx < 16384; idx += NT) {
        const int j4 = idx >> 9, k = (idx >> 2) & 127, jj = idx & 3;
        pW1[idx] = W1[k * 128 + j4 * 4 + jj];   // idx == j4*512 + k*4 + jj
    }
    __syncthreads();

    // ---- h0 = x[:,0] @ Wi^T + bi
    if (t < 512) {
        const int j = t & 127, b = t >> 7;
        float acc = bi[j];
#pragma unroll
        for (int f = 0; f < 16; ++f) acc = fmaf(Wi[j * 16 + f], sx[b * 1024 + f], acc);
        hB[b * 128 + j] = acc;
        hsB[b * 128 + j] = acc;
    }
    // per-thread constant preloads
    const float kb1 = (t < 512) ? b1[t & 127] : 0.0f;
    const float2 bb = *(const float2*)&b2[t * 2];   // biases for rows t*2, t*2+1
    const float4* pw  = PW2 + t;                          // packed stream base
    const float4* r0p = (const float4*)W2 + t * 64;       // fallback: row t*2
    const float4* r1p = r0p + 32;                         // fallback: row t*2+1
    __syncthreads();

    // ---- time loop (63 intervals, sequential)
    for (int i = 0; i < 63; ++i) {
        // Hermite backward-difference coeffs -> dX at 4 RK nodes (waves 0-3)
        if (t < 256) {
            const int f = t & 15, b = (t >> 4) & 3, s = t >> 6;
            const float* xb = &sx[b * 1024];
            const float x0  = xb[i * 16 + f];
            const float x1  = xb[(i + 1) * 16 + f];
            const float seg = (x1 - x0) * rdt;
            const float m0  = (i == 0) ? seg : (x0 - xb[(i - 1) * 16 + f]) * rdt;
            const float c   = (2.0f * seg - 2.0f * m0) * rdt;
            const float d   = (m0 - seg) * rdt * rdt;
            const float ft  = (float)s * (dt * (1.0f / 3.0f));
            sdX[(s * 4 + b) * 16 + f] = fmaf(fmaf(3.0f * d, ft, 2.0f * c), ft, m0);
        }

        for (int s = 0; s < 4; ++s) {
            // ---- GEMM1 (waves 0-7): z[b][k] = tanh(b1 + W1 hs)
            if (t < 512) {
                const int k = t & 127, b = t >> 7;
                float acc = kb1;
#pragma unroll 8
                for (int j4 = 0; j4 < 32; ++j4) {
                    const float4 w = *(const float4*)&pW1[(j4 * 128 + k) * 4]; // lane-consec b128
                    const float4 h = *(const float4*)&hsB[b * 128 + j4 * 4];   // uniform b128
                    acc = fmaf(w.x, h.x, acc); acc = fmaf(w.y, h.y, acc);
                    acc = fmaf(w.z, h.z, acc); acc = fmaf(w.w, h.w, acc);
                }
                zB[b * 128 + k] = tanhf(acc);   // lane-consecutive write
            }
            __syncthreads();

            // ---- GEMM2 (all 16 waves): thread owns rows t*2, t*2+1  (h=t>>3, f-pair=t&7)
            {
                float a[2][4];
#pragma unroll
                for (int j = 0; j < 2; ++j)
#pragma unroll
                    for (int b = 0; b < 4; ++b) a[j][b] = 0.0f;

                float4 w0 = PACKED ? pw[0]    : r0p[0];
                float4 w1 = PACKED ? pw[1024] : r1p[0];
#pragma unroll 2
                for (int kc = 0; kc < 32; ++kc) {
                    const float4 cw0 = w0, cw1 = w1;
                    if (kc < 31) {   // depth-1 prefetch of the coalesced W2 stream
                        if (PACKED) { w0 = pw[(kc + 1) * 2048]; w1 = pw[(kc + 1) * 2048 + 1024]; }
                        else        { w0 = r0p[kc + 1];          w1 = r1p[kc + 1]; }
                    }
#pragma unroll
                    for (int b = 0; b < 4; ++b) {
                        const float4 z = *(const float4*)&zB[b * 128 + kc * 4]; // uniform b128
                        a[0][b] = fmaf(cw0.x, z.x, a[0][b]);
                        a[0][b] = fmaf(cw0.y, z.y, a[0][b]);
                        a[0][b] = fmaf(cw0.z, z.z, a[0][b]);
                        a[0][b] = fmaf(cw0.w, z.w, a[0][b]);
                        a[1][b] = fmaf(cw1.x, z.x, a[1][b]);
                        a[1][b] = fmaf(cw1.y, z.y, a[1][b]);
                        a[1][b] = fmaf(cw1.z, z.z, a[1][b]);
                        a[1][b] = fmaf(cw1.w, z.w, a[1][b]);
                    }
                }
                const int fp = t & 7, hh = t >> 3;
                float kv[4];
#pragma unroll
                for (int b = 0; b < 4; ++b) {
                    const float2 dx2 = *(const float2*)&sdX[(s * 4 + b) * 16 + fp * 2];
                    kv[b] = (a[0][b] + bb.x) * dx2.x + (a[1][b] + bb.y) * dx2.y;
                }
#pragma unroll
                for (int b = 0; b < 4; ++b) {   // reduce the 8 f-pairs of this h
                    kv[b] += __shfl_xor(kv[b], 1);
                    kv[b] += __shfl_xor(kv[b], 2);
                    kv[b] += __shfl_xor(kv[b], 4);
                }
                if (fp == 0) {
#pragma unroll
                    for (int b = 0; b < 4; ++b) skS[(s * 4 + b) * 128 + hh] = kv[b];
                }
            }
            __syncthreads();

            // ---- RK 3/8 stage update (waves 0-7)
            if (t < 512) {
                const int j = t & 127, b = t >> 7;
                const float k1 = skS[(0 * 4 + b) * 128 + j];
                if (s == 3) {
                    const float k2 = skS[(1 * 4 + b) * 128 + j];
                    const float k3 = skS[(2 * 4 + b) * 128 + j];
                    const float k4 = skS[(3 * 4 + b) * 128 + j];
                    const float nh = hB[b * 128 + j]
                                   + dt * 0.125f * (k1 + 3.0f * (k2 + k3) + k4);
                    hB[b * 128 + j]  = nh;
                    hsB[b * 128 + j] = nh;
                } else {
                    const float hv = hB[b * 128 + j];
                    float nh;
                    if (s == 0) {
                        nh = fmaf(dt * (1.0f / 3.0f), k1, hv);
                    } else if (s == 1) {
                        const float k2 = skS[(1 * 4 + b) * 128 + j];
                        nh = hv + dt * k2 - (dt * (1.0f / 3.0f)) * k1;
                    } else {
                        const float k2 = skS[(1 * 4 + b) * 128 + j];
                        const float k3 = skS[(2 * 4 + b) * 128 + j];
                        nh = fmaf(dt, (k1 - k2 + k3), hv);
                    }
                    hsB[b * 128 + j] = nh;
                }
            }
            __syncthreads();
        }
    }

    // ---- write hT
    if (t < 512) {
        const int j = t & 127, b = t >> 7;
        out[(size_t)(b_base + b) * 128 + j] = hB[b * 128 + j];
    }
}

extern "C" void kernel_launch(void* const* d_in, const int* in_sizes, int n_in,
                              void* d_out, int out_size, void* d_ws, size_t ws_size,
                              hipStream_t stream)
{
    (void)in_sizes; (void)n_in; (void)out_size;
    const float* x  = (const float*)d_in[0];
    const float* W1 = (const float*)d_in[1];
    const float* b1 = (const float*)d_in[2];
    const float* W2 = (const float*)d_in[3];
    const float* b2 = (const float*)d_in[4];
    const float* Wi = (const float*)d_in[5];
    const float* bi = (const float*)d_in[6];
    float* o = (float*)d_out;
    float4* PW2 = (float4*)d_ws;
    const bool packed = (ws_size >= (size_t)(2048 * 128 * 4));

    if (packed) {
        hipLaunchKernelGGL(pack_w2_kernel, dim3(256), dim3(256), 0, stream, W2, PW2);
        hipLaunchKernelGGL(HIP_KERNEL_NAME(cde_kernel<true>), dim3(256), dim3(NT), 0, stream,
                           x, W1, b1, W2, b2, Wi, bi, PW2, o);
    } else {
        hipLaunchKernelGGL(HIP_KERNEL_NAME(cde_kernel<false>), dim3(256), dim3(NT), 0, stream,
                           x, W1, b1, W2, b2, Wi, bi, PW2, o);
    }
}